// Round 4
// baseline (470.581 us; speedup 1.0000x reference)
//
#include <hip/hip_runtime.h>

// SAN Subtraction: x[8,64,56,56] fp32, K=7, stride=1, pad=3 (reflect), dil=1
// out[n,c,i*7+j, h*56+w] = x[n,c,h,w] - x[n,c, refl(h+i-3), refl(w+j-3)]
// out = [8,64,49,3136] fp32 = 314.7 MB -> write floor ~52 us @ 6.3 TB/s.
//
// R4: MEASUREMENT ROUND. Body = R2 kernel (best so far, nt stores),
// launched 4x back-to-back (idempotent -> correct). Timed delta vs R2's
// 309.8 us isolates the kernel's true standalone time K = (dur-310)/3,
// which the rocprof top-5 filter hides (all top dispatches are ~200us
// harness poison fills; our kernel is <196us and invisible).
// Decision rule: K<=70 -> kernel at write roofline, revert+declare.
//                K>=100 -> ~55us headroom, attack store path with known baseline.

#define HH 56
#define WW 56
#define KK 7
#define PP 3
#define KK2 49            // K*K
#define LL (HH * WW)      // 3136
#define LL4 (LL / 4)      // 784 float4 per (plane,k) slice
#define NPL 512           // N*C planes
#define NTHREADS (NPL * KK * LL4)   // 2,809,856 = 10976 * 256 exactly

typedef float v4f __attribute__((ext_vector_type(4)));

__global__ __launch_bounds__(256) void san_sub_kernel(
        const float* __restrict__ x, float* __restrict__ out) {
    int tid = blockIdx.x * 256 + threadIdx.x;   // exact grid: no bounds check

    int l4    = tid % LL4;
    int rest  = tid / LL4;
    int i     = rest % KK;       // kernel row 0..6
    int plane = rest / KK;       // 0..511

    int h  = l4 / (WW / 4);      // 0..55
    int w4 = l4 - h * (WW / 4);  // 0..13
    int w  = w4 * 4;             // 0,4,...,52

    const float* xp = x + (long)plane * LL;

    // center: one aligned 16B load (L1/L2 hit; shared across the 7 i-threads)
    v4f c = *reinterpret_cast<const v4f*>(xp + h * WW + w);

    // row reflection (p=3 < 56: single bounce), folded into the load address
    int r = h + i - PP;
    r = (r < 0) ? -r : r;
    r = (r >= HH) ? (2 * HH - 2 - r) : r;

    bool isL = (w4 == 0);            // needs cols -3..-1 reflected
    bool isR = (w4 == 13);           // needs cols 56..58 reflected
    int base = isL ? 0 : (isR ? (WW - 12) : (w - 4));   // 16B-aligned, in-bounds

    const float* row = xp + r * WW + base;
    v4f a0 = *reinterpret_cast<const v4f*>(row);
    v4f a1 = *reinterpret_cast<const v4f*>(row + 4);
    v4f a2 = *reinterpret_cast<const v4f*>(row + 8);
    float rr[12] = {a0.x, a0.y, a0.z, a0.w,
                    a1.x, a1.y, a1.z, a1.w,
                    a2.x, a2.y, a2.z, a2.w};

    // virt[t] = x[plane][r][refl(w-3+t)], t = 0..9; compile-time reg indices,
    // border remap is 2 cndmask per element (only lanes w4==0 / w4==13 differ)
    float virt[10];
    #pragma unroll
    for (int t = 0; t < 10; ++t) {
        const int iInt = t + 1;                         // base = w-4: col w-3+t
        const int iLft = (t < 3) ? (3 - t) : (t - 3);   // base = 0:   col refl(t-3)
        const int iRgt = (t <= 6) ? (t + 5) : (17 - t); // base = 44:  col refl(49+t)
        virt[t] = isL ? rr[iLft] : (isR ? rr[iRgt] : rr[iInt]);
    }

    // 7 outputs for this kernel row: windows j..j+3 of virt
    v4f* o4 = reinterpret_cast<v4f*>(out) + ((long)plane * KK2 + i * KK) * LL4 + l4;
    #pragma unroll
    for (int j = 0; j < KK; ++j) {
        v4f rv;
        rv.x = c.x - virt[j + 0];
        rv.y = c.y - virt[j + 1];
        rv.z = c.z - virt[j + 2];
        rv.w = c.w - virt[j + 3];
        __builtin_nontemporal_store(rv, o4 + j * LL4);
    }
}

extern "C" void kernel_launch(void* const* d_in, const int* in_sizes, int n_in,
                              void* d_out, int out_size, void* d_ws, size_t ws_size,
                              hipStream_t stream) {
    const float* x = (const float*)d_in[0];
    float* out = (float*)d_out;
    int block = 256;
    int grid = NTHREADS / block;   // 10976 blocks, exact cover
    // 4x launch: idempotent output; timed delta vs single-launch baseline
    // (309.8 us) isolates the kernel's standalone duration K = (dur-310)/3.
    san_sub_kernel<<<grid, block, 0, stream>>>(x, out);
    san_sub_kernel<<<grid, block, 0, stream>>>(x, out);
    san_sub_kernel<<<grid, block, 0, stream>>>(x, out);
    san_sub_kernel<<<grid, block, 0, stream>>>(x, out);
}

// Round 5
// 309.384 us; speedup vs baseline: 1.5210x; 1.5210x over previous
//
#include <hip/hip_runtime.h>

// SAN Subtraction: x[8,64,56,56] fp32, K=7, stride=1, pad=3 (reflect), dil=1
// out[n,c,i*7+j, h*56+w] = x[n,c,h,w] - x[n,c, refl(h+i-3), refl(w+j-3)]
// out = [8,64,49,3136] fp32 = 314.7 MB.
//
// R5 (FINAL): revert to single-launch R2 kernel — session best.
// R4's 4x-launch measurement isolated the kernel's standalone time:
//   K = (470.6 - 309.8)/3 = 53.6 us  ->  5.9 TB/s effective write BW
//   = 93% of the 6.33 TB/s ceiling the harness's own 1.26GB fill
//   dispatches achieve on this box (write floor = 314.7MB/6.33TB/s = 50us).
// The remaining ~256 us of dur_us is serialized harness output-poisoning
// (the ~200us fillBufferAligned + smaller resets), outside kernel control.
// Kernel is at the store-BW roofline.

#define HH 56
#define WW 56
#define KK 7
#define PP 3
#define KK2 49            // K*K
#define LL (HH * WW)      // 3136
#define LL4 (LL / 4)      // 784 float4 per (plane,k) slice
#define NPL 512           // N*C planes
#define NTHREADS (NPL * KK * LL4)   // 2,809,856 = 10976 * 256 exactly

typedef float v4f __attribute__((ext_vector_type(4)));

__global__ __launch_bounds__(256) void san_sub_kernel(
        const float* __restrict__ x, float* __restrict__ out) {
    int tid = blockIdx.x * 256 + threadIdx.x;   // exact grid: no bounds check

    int l4    = tid % LL4;
    int rest  = tid / LL4;
    int i     = rest % KK;       // kernel row 0..6
    int plane = rest / KK;       // 0..511

    int h  = l4 / (WW / 4);      // 0..55
    int w4 = l4 - h * (WW / 4);  // 0..13
    int w  = w4 * 4;             // 0,4,...,52

    const float* xp = x + (long)plane * LL;

    // center: one aligned 16B load (L1/L2 hit; shared across the 7 i-threads)
    v4f c = *reinterpret_cast<const v4f*>(xp + h * WW + w);

    // row reflection (p=3 < 56: single bounce), folded into the load address
    int r = h + i - PP;
    r = (r < 0) ? -r : r;
    r = (r >= HH) ? (2 * HH - 2 - r) : r;

    bool isL = (w4 == 0);            // needs cols -3..-1 reflected
    bool isR = (w4 == 13);           // needs cols 56..58 reflected
    int base = isL ? 0 : (isR ? (WW - 12) : (w - 4));   // 16B-aligned, in-bounds

    const float* row = xp + r * WW + base;
    v4f a0 = *reinterpret_cast<const v4f*>(row);
    v4f a1 = *reinterpret_cast<const v4f*>(row + 4);
    v4f a2 = *reinterpret_cast<const v4f*>(row + 8);
    float rr[12] = {a0.x, a0.y, a0.z, a0.w,
                    a1.x, a1.y, a1.z, a1.w,
                    a2.x, a2.y, a2.z, a2.w};

    // virt[t] = x[plane][r][refl(w-3+t)], t = 0..9; compile-time reg indices,
    // border remap is 2 cndmask per element (only lanes w4==0 / w4==13 differ)
    float virt[10];
    #pragma unroll
    for (int t = 0; t < 10; ++t) {
        const int iInt = t + 1;                         // base = w-4: col w-3+t
        const int iLft = (t < 3) ? (3 - t) : (t - 3);   // base = 0:   col refl(t-3)
        const int iRgt = (t <= 6) ? (t + 5) : (17 - t); // base = 44:  col refl(49+t)
        virt[t] = isL ? rr[iLft] : (isR ? rr[iRgt] : rr[iInt]);
    }

    // 7 outputs for this kernel row: windows j..j+3 of virt
    v4f* o4 = reinterpret_cast<v4f*>(out) + ((long)plane * KK2 + i * KK) * LL4 + l4;
    #pragma unroll
    for (int j = 0; j < KK; ++j) {
        v4f rv;
        rv.x = c.x - virt[j + 0];
        rv.y = c.y - virt[j + 1];
        rv.z = c.z - virt[j + 2];
        rv.w = c.w - virt[j + 3];
        __builtin_nontemporal_store(rv, o4 + j * LL4);
    }
}

extern "C" void kernel_launch(void* const* d_in, const int* in_sizes, int n_in,
                              void* d_out, int out_size, void* d_ws, size_t ws_size,
                              hipStream_t stream) {
    const float* x = (const float*)d_in[0];
    float* out = (float*)d_out;
    int block = 256;
    int grid = NTHREADS / block;   // 10976 blocks, exact cover
    san_sub_kernel<<<grid, block, 0, stream>>>(x, out);
}